// Round 1
// baseline (582.299 us; speedup 1.0000x reference)
//
#include <hip/hip_runtime.h>

#define LOG2E 1.4426950408889634f
#define LN2   0.6931471805599453f

#define NB 256
#define SS 1024
#define NT 64
#define NL 32

__device__ __forceinline__ float wmax(float v){
  v = fmaxf(v, __shfl_xor(v,1));
  v = fmaxf(v, __shfl_xor(v,2));
  v = fmaxf(v, __shfl_xor(v,4));
  v = fmaxf(v, __shfl_xor(v,8));
  v = fmaxf(v, __shfl_xor(v,16));
  v = fmaxf(v, __shfl_xor(v,32));
  return v;
}
__device__ __forceinline__ float wsum(float v){
  v += __shfl_xor(v,1);
  v += __shfl_xor(v,2);
  v += __shfl_xor(v,4);
  v += __shfl_xor(v,8);
  v += __shfl_xor(v,16);
  v += __shfl_xor(v,32);
  return v;
}

// One wave (64 lanes) per batch. lane = tag j. alpha kept in log2 domain.
__global__ void __launch_bounds__(64)
patcrf_fwd(const float* __restrict__ le, const float* __restrict__ pe,
           const int* __restrict__ y, const float* __restrict__ lt,
           const int* __restrict__ t2l, const float* __restrict__ tp,
           const float* __restrict__ tc, const unsigned int* __restrict__ smask,
           float* __restrict__ out)
{
  const int b = blockIdx.x;
  const int lane = threadIdx.x;

  __shared__ __align__(16) float p_lds[NT];
  __shared__ float trans_lds[NT*NT];   // natural-log transitions (for score gather)
  __shared__ __align__(16) float tp_lds[NT*4];
  __shared__ int y_lds[SS];
  __shared__ int t2l_lds[NT];

  // ---- stage small tables (single wave: lockstep, one barrier for safety) ----
  t2l_lds[lane] = t2l[lane];
  float4 mytp = *(const float4*)(tp + lane*4);
  *(float4*)(tp_lds + lane*4) = mytp;
  const int* yb = y + b*SS;
  #pragma unroll
  for (int k=0;k<SS/NT;k++) y_lds[k*NT+lane] = yb[k*NT+lane];
  __syncthreads();

  const int myl = t2l_lds[lane];

  // W column in registers: w[i] = exp(trans[i][lane]) (base-2 scaled)
  float w[NT];
  #pragma unroll
  for (int i=0;i<NT;i++){
    float tn = lt[t2l_lds[i]*NL + myl] + tc[i*NT + lane];
    trans_lds[i*NT + lane] = tn;
    w[i] = __builtin_amdgcn_exp2f(tn * LOG2E);
  }
  __syncthreads();

  // ---- score phase: emission + transition sums, lanes parallel over s ----
  const float* leb = le + (size_t)b*SS*NL;
  const float* peb = pe + (size_t)b*SS*4;
  float sc = 0.0f;
  #pragma unroll
  for (int k=0;k<SS/NT;k++){
    int s = k*NT + lane;
    int ys = y_lds[s];
    float xv = leb[s*NL + t2l_lds[ys]];
    float4 p4 = *(const float4*)(peb + (size_t)s*4);
    float4 t4 = *(const float4*)(tp_lds + ys*4);
    xv += p4.x*t4.x + p4.y*t4.y + p4.z*t4.z + p4.w*t4.w;
    sc += xv;
    if (s < SS-1) sc += trans_lds[ys*NT + y_lds[s+1]];
  }

  // ---- start-mask representation sniff (bool bytes vs int32 vs float32) ----
  bool all01 = true, allf = true;
  #pragma unroll
  for (int k=0;k<16;k++){
    unsigned int v = smask[k];
    all01 = all01 && (v <= 1u);
    allf  = allf  && (v == 0u || v == 0x3F800000u);
  }
  int startv;
  if (all01)      startv = ((const int*)smask)[lane];
  else if (allf)  startv = (((const unsigned int*)smask)[lane] != 0u) ? 1 : 0;
  else            startv = ((const unsigned char*)smask)[lane];

  // ---- init alpha (s=0), log2 domain ----
  float4 pe0 = *(const float4*)peb;
  float x0 = leb[myl] + pe0.x*mytp.x + pe0.y*mytp.y + pe0.z*mytp.z + pe0.w*mytp.w;
  float alpha2 = startv ? x0*LOG2E : -10000.0f*LOG2E;

  // ---- forward scan, depth-4 prefetch ----
#define STEP(LEV, PEV) do { \
    float x2_ = (LEV + (PEV).x*mytp.x + (PEV).y*mytp.y + (PEV).z*mytp.z + (PEV).w*mytp.w) * LOG2E; \
    float m_ = wmax(alpha2); \
    float pv_ = __builtin_amdgcn_exp2f(alpha2 - m_); \
    p_lds[lane] = pv_; \
    __builtin_amdgcn_wave_barrier(); \
    float a0_=0.f,a1_=0.f,a2_=0.f,a3_=0.f; \
    _Pragma("unroll") \
    for (int i_=0;i_<NT;i_+=4){ \
      float4 pq_ = *(const float4*)(p_lds + i_); \
      a0_ = fmaf(pq_.x, w[i_+0], a0_); \
      a1_ = fmaf(pq_.y, w[i_+1], a1_); \
      a2_ = fmaf(pq_.z, w[i_+2], a2_); \
      a3_ = fmaf(pq_.w, w[i_+3], a3_); \
    } \
    __builtin_amdgcn_wave_barrier(); \
    alpha2 = m_ + __builtin_amdgcn_logf((a0_+a1_)+(a2_+a3_)) + x2_; \
  } while(0)

  float  lec[4];
  float4 pec[4];
  #pragma unroll
  for (int k=0;k<4;k++){
    int s = 1+k;
    lec[k] = leb[s*NL + myl];
    pec[k] = *(const float4*)(peb + (size_t)s*4);
  }
  int s0 = 1;
  for (int g=0; g<255; ++g){
    float len[4]; float4 pen[4];
    #pragma unroll
    for (int k=0;k<4;k++){
      int s = s0 + 4 + k; if (s > SS-1) s = SS-1;
      len[k] = leb[s*NL + myl];
      pen[k] = *(const float4*)(peb + (size_t)s*4);
    }
    STEP(lec[0], pec[0]);
    STEP(lec[1], pec[1]);
    STEP(lec[2], pec[2]);
    STEP(lec[3], pec[3]);
    #pragma unroll
    for (int k=0;k<4;k++){ lec[k]=len[k]; pec[k]=pen[k]; }
    s0 += 4;
  }
  // tail: s = 1021,1022,1023 (already prefetched into lec/pec)
  STEP(lec[0], pec[0]);
  STEP(lec[1], pec[1]);
  STEP(lec[2], pec[2]);
#undef STEP

  // ---- finalize: logZ and output ----
  float m = wmax(alpha2);
  float ssum = wsum(__builtin_amdgcn_exp2f(alpha2 - m));
  float logZ = (m + __builtin_amdgcn_logf(ssum)) * LN2;
  float tot = wsum(sc);
  if (lane == 0) out[b] = tot - logZ;
}

extern "C" void kernel_launch(void* const* d_in, const int* in_sizes, int n_in,
                              void* d_out, int out_size, void* d_ws, size_t ws_size,
                              hipStream_t stream)
{
  patcrf_fwd<<<NB, NT, 0, stream>>>(
    (const float*)d_in[0],          // label_emissions [B,S,32]
    (const float*)d_in[1],          // pattern_emissions [B,S,4]
    (const int*)d_in[2],            // y [B,S]
    (const float*)d_in[3],          // label_transitions [32,32]
    (const int*)d_in[4],            // tag2label [64]
    (const float*)d_in[5],          // tag_patterns [64,4]
    (const float*)d_in[6],          // transition_constraints [64,64]
    (const unsigned int*)d_in[7],   // start_mask [64] (repr sniffed)
    (float*)d_out);
}

// Round 2
// 345.747 us; speedup vs baseline: 1.6842x; 1.6842x over previous
//
#include <hip/hip_runtime.h>

#define LOG2E 1.4426950408889634f
#define LN2   0.6931471805599453f

#define NB 256
#define SS 1024
#define NT 64
#define NL 32

// Pure-VALU wave64 reductions via DPP: row_shr 1/2/4/8, row_bcast15, row_bcast31,
// result in lane 63, broadcast with readlane.
__device__ __forceinline__ float wave_max64(float v){
#define DMAX(ctrl) { int _t = __builtin_amdgcn_update_dpp(__float_as_int(v), __float_as_int(v), ctrl, 0xF, 0xF, false); \
                     v = fmaxf(v, __int_as_float(_t)); }
  DMAX(0x111) DMAX(0x112) DMAX(0x114) DMAX(0x118) DMAX(0x142) DMAX(0x143)
#undef DMAX
  return __int_as_float(__builtin_amdgcn_readlane(__float_as_int(v), 63));
}
__device__ __forceinline__ float wave_sum64(float v){
#define DADD(ctrl) { int _t = __builtin_amdgcn_update_dpp(0, __float_as_int(v), ctrl, 0xF, 0xF, false); \
                     v = v + __int_as_float(_t); }
  DADD(0x111) DADD(0x112) DADD(0x114) DADD(0x118) DADD(0x142) DADD(0x143)
#undef DADD
  return __int_as_float(__builtin_amdgcn_readlane(__float_as_int(v), 63));
}

// One wave (64 lanes) per batch. lane = tag j.
// Scaled product domain: alpha2_j = log2(p_j) + L2 (L2 lane-uniform).
__global__ void __launch_bounds__(64)
patcrf_fwd(const float* __restrict__ le, const float* __restrict__ pe,
           const int* __restrict__ y, const float* __restrict__ lt,
           const int* __restrict__ t2l, const float* __restrict__ tp,
           const float* __restrict__ tc, const unsigned int* __restrict__ smask,
           float* __restrict__ out)
{
  const int b = blockIdx.x;
  const int lane = threadIdx.x;

  __shared__ __align__(16) float p_lds[NT];
  __shared__ float trans_lds[NT*NT];   // natural-log transitions (score gather)
  __shared__ __align__(16) float tp_lds[NT*4];
  __shared__ int y_lds[SS];
  __shared__ int t2l_lds[NT];

  // ---- stage small tables ----
  t2l_lds[lane] = t2l[lane];
  float4 mytp = *(const float4*)(tp + lane*4);
  *(float4*)(tp_lds + lane*4) = mytp;
  const int* yb = y + b*SS;
  #pragma unroll
  for (int k=0;k<SS/NT;k++) y_lds[k*NT+lane] = yb[k*NT+lane];
  __syncthreads();

  const int myl = t2l_lds[lane];

  // W column in registers: w[i] = exp(trans[i][lane])
  float w[NT];
  #pragma unroll
  for (int i=0;i<NT;i++){
    float tn = lt[t2l_lds[i]*NL + myl] + tc[i*NT + lane];
    trans_lds[i*NT + lane] = tn;
    w[i] = __builtin_amdgcn_exp2f(tn * LOG2E);
  }
  __syncthreads();

  // ---- score phase: emission + transition sums, lanes parallel over s ----
  const float* leb = le + (size_t)b*SS*NL;
  const float* peb = pe + (size_t)b*SS*4;
  float sc = 0.0f;
  #pragma unroll
  for (int k=0;k<SS/NT;k++){
    int s = k*NT + lane;
    int ys = y_lds[s];
    float xv = leb[s*NL + t2l_lds[ys]];
    float4 p4 = *(const float4*)(peb + (size_t)s*4);
    float4 t4 = *(const float4*)(tp_lds + ys*4);
    xv += p4.x*t4.x + p4.y*t4.y + p4.z*t4.z + p4.w*t4.w;
    sc += xv;
    if (s < SS-1) sc += trans_lds[ys*NT + y_lds[s+1]];
  }

  // ---- start-mask representation sniff (bool bytes vs int32 vs float32) ----
  bool all01 = true, allf = true;
  #pragma unroll
  for (int k=0;k<16;k++){
    unsigned int v = smask[k];
    all01 = all01 && (v <= 1u);
    allf  = allf  && (v == 0u || v == 0x3F800000u);
  }
  int startv;
  if (all01)      startv = ((const int*)smask)[lane];
  else if (allf)  startv = (((const unsigned int*)smask)[lane] != 0u) ? 1 : 0;
  else            startv = ((const unsigned char*)smask)[lane];

  // ---- init alpha (s=0) ----
  float4 pe0 = *(const float4*)peb;
  float x0 = leb[myl] + pe0.x*mytp.x + pe0.y*mytp.y + pe0.z*mytp.z + pe0.w*mytp.w;
  float a20 = startv ? x0*LOG2E : -14427.0f;
  float mx0 = wave_max64(a20);
  float pj  = __builtin_amdgcn_exp2f(a20 - mx0);   // p normalized so max=1
  float L2  = mx0;
  p_lds[lane] = pj;

  // ---- prologue: e2/mx for steps 1..4; raw emissions for steps 5..8 ----
  float e2c[4], mxc[4];
  float lec[4]; float4 pec[4];
  #pragma unroll
  for (int k=0;k<4;k++){
    int s = 1+k;
    float lev = leb[s*NL + myl];
    float4 pev = *(const float4*)(peb + (size_t)s*4);
    float x2 = (lev + pev.x*mytp.x + pev.y*mytp.y + pev.z*mytp.z + pev.w*mytp.w) * LOG2E;
    mxc[k] = wave_max64(x2);
    e2c[k] = __builtin_amdgcn_exp2f(x2 - mxc[k]);
  }
  #pragma unroll
  for (int k=0;k<4;k++){
    int s = 5+k;
    lec[k] = leb[s*NL + myl];
    pec[k] = *(const float4*)(peb + (size_t)s*4);
  }

  // one step: p(LDS) -> q = (W^T p) * e2 ; L2 += mx.  exp/log/max all off-chain.
#define STEP(E2, MX) do { \
    __builtin_amdgcn_wave_barrier(); \
    float a0=0.f,a1=0.f,a2=0.f,a3=0.f; \
    _Pragma("unroll") \
    for (int i_=0;i_<NT;i_+=4){ \
      float4 pq = *(const float4*)(p_lds + i_); \
      a0 = fmaf(pq.x, w[i_+0], a0); \
      a1 = fmaf(pq.y, w[i_+1], a1); \
      a2 = fmaf(pq.z, w[i_+2], a2); \
      a3 = fmaf(pq.w, w[i_+3], a3); \
    } \
    pj = ((a0+a1)+(a2+a3)) * (E2); \
    L2 += (MX); \
  } while(0)

  // main loop: 255 groups of 4 steps (t = 1..1020), renorm once per group
  for (int g=0; g<255; ++g){
    const int t0 = 1 + 4*g;
    // issue loads for steps t0+8..t0+11 (consumed next group)
    float len[4]; float4 pen[4];
    #pragma unroll
    for (int k=0;k<4;k++){
      int s = t0 + 8 + k; if (s > SS-1) s = SS-1;
      len[k] = leb[s*NL + myl];
      pen[k] = *(const float4*)(peb + (size_t)s*4);
    }
    // compute e2/mx for steps t0+4..t0+7 from last group's raw loads (off-chain)
    float e2n[4], mxn[4];
    #pragma unroll
    for (int k=0;k<4;k++){
      float x2 = (lec[k] + pec[k].x*mytp.x + pec[k].y*mytp.y + pec[k].z*mytp.z + pec[k].w*mytp.w) * LOG2E;
      mxn[k] = wave_max64(x2);
      e2n[k] = __builtin_amdgcn_exp2f(x2 - mxn[k]);
    }

    STEP(e2c[0], mxc[0]); p_lds[lane] = pj;
    STEP(e2c[1], mxc[1]); p_lds[lane] = pj;
    STEP(e2c[2], mxc[2]); p_lds[lane] = pj;
    STEP(e2c[3], mxc[3]);
    // renorm (only on-chain reduction, 1 per 4 steps)
    float s4 = wave_sum64(pj);
    float r  = __builtin_amdgcn_rcpf(s4);
    L2 += __builtin_amdgcn_logf(s4);       // v_log_f32 = log2
    pj *= r;
    p_lds[lane] = pj;

    #pragma unroll
    for (int k=0;k<4;k++){ e2c[k]=e2n[k]; mxc[k]=mxn[k]; lec[k]=len[k]; pec[k]=pen[k]; }
  }

  // tail: steps 1021..1023 (e2c/mxc hold 1021..1024; [3] unused)
  STEP(e2c[0], mxc[0]); p_lds[lane] = pj;
  STEP(e2c[1], mxc[1]); p_lds[lane] = pj;
  STEP(e2c[2], mxc[2]);
#undef STEP

  // ---- finalize ----
  float sf   = wave_sum64(pj);
  float logZ = (L2 + __builtin_amdgcn_logf(sf)) * LN2;
  float tot  = wave_sum64(sc);
  if (lane == 0) out[b] = tot - logZ;
}

extern "C" void kernel_launch(void* const* d_in, const int* in_sizes, int n_in,
                              void* d_out, int out_size, void* d_ws, size_t ws_size,
                              hipStream_t stream)
{
  patcrf_fwd<<<NB, NT, 0, stream>>>(
    (const float*)d_in[0],          // label_emissions [B,S,32]
    (const float*)d_in[1],          // pattern_emissions [B,S,4]
    (const int*)d_in[2],            // y [B,S]
    (const float*)d_in[3],          // label_transitions [32,32]
    (const int*)d_in[4],            // tag2label [64]
    (const float*)d_in[5],          // tag_patterns [64,4]
    (const float*)d_in[6],          // transition_constraints [64,64]
    (const unsigned int*)d_in[7],   // start_mask [64] (repr sniffed)
    (float*)d_out);
}

// Round 3
// 271.024 us; speedup vs baseline: 2.1485x; 1.2757x over previous
//
#include <hip/hip_runtime.h>

#define LOG2E 1.4426950408889634f
#define LN2   0.6931471805599453f

#define NB 256
#define SS 1024
#define NT 64
#define NL 32
#define RSTR 72          // replica stride (floats): conflict-free reads
#define PSC 8.0f         // constant per-step pre-scale (bits)

// wave64 all-lane sum via DPP cascade, broadcast from lane 63
__device__ __forceinline__ float wave_sum64(float v){
#define DADD(ctrl) { int _t = __builtin_amdgcn_update_dpp(0, __float_as_int(v), ctrl, 0xF, 0xF, false); \
                     v = v + __int_as_float(_t); }
  DADD(0x111) DADD(0x112) DADD(0x114) DADD(0x118) DADD(0x142) DADD(0x143)
#undef DADD
  return __int_as_float(__builtin_amdgcn_readlane(__float_as_int(v), 63));
}

// all-reduce sum within each 4-lane quad (2 quad_perm DPP)
__device__ __forceinline__ float quad_sum(float v){
  int t1 = __builtin_amdgcn_update_dpp(0, __float_as_int(v), 0xB1, 0xF, 0xF, false);
  v += __int_as_float(t1);
  int t2 = __builtin_amdgcn_update_dpp(0, __float_as_int(v), 0x4E, 0xF, 0xF, false);
  v += __int_as_float(t2);
  return v;
}

// 4 waves per batch. wave w owns outputs j in [16w,16w+16).
// lane = jj*4+ii: output j = 16w+jj, source range i in [16ii, 16ii+16).
// p in LDS, 4 replicas (stride RSTR), double-buffered; ONE barrier per step.
// Scaled product domain: alpha_j = p_j * 2^(L2 + PSC*(t+1)) with pipelined renorm.
__global__ void __launch_bounds__(256)
patcrf_fwd(const float* __restrict__ le, const float* __restrict__ pe,
           const int* __restrict__ y, const float* __restrict__ lt,
           const int* __restrict__ t2l, const float* __restrict__ tp,
           const float* __restrict__ tc, const unsigned int* __restrict__ smask,
           float* __restrict__ out)
{
  const int b = blockIdx.x;
  const int tid = threadIdx.x;
  const int wv = tid >> 6;
  const int lane = tid & 63;
  const int jj = lane >> 2, ii = lane & 3;
  const int j = wv*16 + jj;

  __shared__ __align__(16) float pbuf[2][4*RSTR];
  __shared__ __align__(16) float sums[4];
  __shared__ __align__(16) float scpart[4];
  __shared__ float trans_lds[NT*NT];     // natural-log transitions
  __shared__ __align__(16) float tp_lds[NT*4];
  __shared__ int y_lds[SS];
  __shared__ int t2l_lds[NT];

  const int* yb = y + b*SS;
  if (tid < NT){
    t2l_lds[tid] = t2l[tid];
    *(float4*)(tp_lds + tid*4) = *(const float4*)(tp + tid*4);
  }
  *(int4*)(y_lds + tid*4) = *(const int4*)(yb + tid*4);
  __syncthreads();

  #pragma unroll
  for (int k=0;k<16;k++){
    int idx = k*256 + tid;
    int i_ = idx >> 6, j_ = idx & 63;
    trans_lds[idx] = lt[t2l_lds[i_]*NL + t2l_lds[j_]] + tc[idx];
  }
  __syncthreads();

  const int myl = t2l_lds[j];
  const float4 mytp = *(const float4*)(tp_lds + j*4);

  // per-lane weights: wk[k] = exp(trans[16*ii+k][j])
  float wk[16];
  #pragma unroll
  for (int k=0;k<16;k++)
    wk[k] = __builtin_amdgcn_exp2f(trans_lds[(16*ii+k)*NT + j] * LOG2E);

  // ---- score phase: 256 threads over s ----
  const float* leb = le + (size_t)b*SS*NL;
  const float* peb = pe + (size_t)b*SS*4;
  float sc = 0.f;
  #pragma unroll
  for (int k=0;k<4;k++){
    int s = tid + 256*k;
    int ys = y_lds[s];
    float xv = leb[(size_t)s*NL + t2l_lds[ys]];
    float4 p4 = *(const float4*)(peb + (size_t)s*4);
    float4 t4 = *(const float4*)(tp_lds + ys*4);
    xv += p4.x*t4.x + p4.y*t4.y + p4.z*t4.z + p4.w*t4.w;
    sc += xv;
    if (s < SS-1) sc += trans_lds[ys*NT + y_lds[s+1]];
  }
  {
    float scw = wave_sum64(sc);
    if (lane==0) scpart[wv] = scw;
  }

  // ---- start-mask sniff + p0 ----
  bool all01 = true, allf = true;
  #pragma unroll
  for (int k=0;k<16;k++){
    unsigned int v = smask[k];
    all01 = all01 && (v <= 1u);
    allf  = allf  && (v == 0u || v == 0x3F800000u);
  }
  int startv;
  if (all01)      startv = ((const int*)smask)[j];
  else if (allf)  startv = (((const unsigned int*)smask)[j] != 0u) ? 1 : 0;
  else            startv = ((const unsigned char*)smask)[j];

  float4 pe0 = *(const float4*)peb;
  float x0 = leb[myl] + pe0.x*mytp.x + pe0.y*mytp.y + pe0.z*mytp.z + pe0.w*mytp.w;
  float p0 = startv ? __builtin_amdgcn_exp2f(x0*LOG2E - PSC) : 0.f;
  pbuf[1][ii*RSTR + j] = p0;                 // t=1 reads buf 1
  {
    float ws0 = wave_sum64(p0);              // = 4 * sum over wave's j
    if (lane==0) sums[wv] = ws0;
  }

  // ---- prologue: e2 for t=1..4; raw loads for t=5..8 ----
  float e2c[4]; float lec[4]; float4 pec[4];
  #pragma unroll
  for (int k=0;k<4;k++){
    int s = 1+k;
    float lev = leb[(size_t)s*NL + myl];
    float4 pev = *(const float4*)(peb + (size_t)s*4);
    float x2 = (lev + pev.x*mytp.x + pev.y*mytp.y + pev.z*mytp.z + pev.w*mytp.w)*LOG2E;
    e2c[k] = __builtin_amdgcn_exp2f(x2 - PSC);
  }
  #pragma unroll
  for (int k=0;k<4;k++){
    int s = 5+k;
    lec[k] = leb[(size_t)s*NL + myl];
    pec[k] = *(const float4*)(peb + (size_t)s*4);
  }
  __syncthreads();

  const float* rb0 = &pbuf[0][ii*RSTR + 16*ii];
  const float* rb1 = &pbuf[1][ii*RSTR + 16*ii];
  float* wb0 = &pbuf[0][ii*RSTR + j];
  float* wb1 = &pbuf[1][ii*RSTR + j];

  float q = 0.f, L2 = 0.f;

#define STEP(RB, WP, E2) do { \
    float4 P0 = *(const float4*)((RB) + 0); \
    float4 P1 = *(const float4*)((RB) + 4); \
    float4 P2 = *(const float4*)((RB) + 8); \
    float4 P3 = *(const float4*)((RB) + 12); \
    float a0 = P0.x*wk[0];  a0 = fmaf(P0.y,wk[1],a0);  a0 = fmaf(P0.z,wk[2],a0);  a0 = fmaf(P0.w,wk[3],a0); \
    float a1 = P1.x*wk[4];  a1 = fmaf(P1.y,wk[5],a1);  a1 = fmaf(P1.z,wk[6],a1);  a1 = fmaf(P1.w,wk[7],a1); \
    float a2 = P2.x*wk[8];  a2 = fmaf(P2.y,wk[9],a2);  a2 = fmaf(P2.z,wk[10],a2); a2 = fmaf(P2.w,wk[11],a2); \
    float a3 = P3.x*wk[12]; a3 = fmaf(P3.y,wk[13],a3); a3 = fmaf(P3.z,wk[14],a3); a3 = fmaf(P3.w,wk[15],a3); \
    float qv = (a0+a1)+(a2+a3); \
    qv = quad_sum(qv); \
    qv *= (E2); \
    *(WP) = qv; \
    q = qv; \
} while(0)

  // main loop: groups of 4 steps, t = 1..1020 (odd t reads buf1)
  for (int g=0; g<255; ++g){
    const int t0 = 1 + 4*g;
    float len[4]; float4 pen[4];
    #pragma unroll
    for (int k=0;k<4;k++){
      int s = t0 + 8 + k; if (s > SS-1) s = SS-1;
      len[k] = leb[(size_t)s*NL + myl];
      pen[k] = *(const float4*)(peb + (size_t)s*4);
    }
    float e2n[4];
    #pragma unroll
    for (int k=0;k<4;k++){
      float x2 = (lec[k] + pec[k].x*mytp.x + pec[k].y*mytp.y + pec[k].z*mytp.z + pec[k].w*mytp.w)*LOG2E;
      e2n[k] = __builtin_amdgcn_exp2f(x2 - PSC);
    }

    // k0 (odd t): read sums from previous group's k3 (off-chain)
    STEP(rb1, wb0, e2c[0]);
    float4 sv = *(const float4*)sums;
    __syncthreads();
    float S = (sv.x+sv.y)+(sv.z+sv.w);
    float scale = __builtin_amdgcn_rcpf(S);
    L2 += __builtin_amdgcn_logf(S);          // v_log_f32 = log2
    float e2s = e2c[1]*scale;

    STEP(rb0, wb1, e2s);
    __syncthreads();

    STEP(rb1, wb0, e2c[2]);
    __syncthreads();

    STEP(rb0, wb1, e2c[3]);
    {
      float ws = wave_sum64(q);
      if (lane==0) sums[wv] = ws;
    }
    __syncthreads();

    #pragma unroll
    for (int k=0;k<4;k++){ e2c[k]=e2n[k]; lec[k]=len[k]; pec[k]=pen[k]; }
  }

  // tail: t = 1021, 1022, 1023
  STEP(rb1, wb0, e2c[0]);
  float4 sv = *(const float4*)sums;
  __syncthreads();
  {
    float S = (sv.x+sv.y)+(sv.z+sv.w);
    float scale = __builtin_amdgcn_rcpf(S);
    L2 += __builtin_amdgcn_logf(S);
    float e2s = e2c[1]*scale;
    STEP(rb0, wb1, e2s);
  }
  __syncthreads();
  STEP(rb1, wb0, e2c[2]);
#undef STEP

  // ---- finalize ----
  {
    float wsf = wave_sum64(q);               // = 4 * sum over wave's j
    if (lane==0) sums[wv] = wsf;
  }
  __syncthreads();
  if (tid == 0){
    float Sf = (sums[0]+sums[1])+(sums[2]+sums[3]);        // = 4 * total
    float sct = (scpart[0]+scpart[1])+(scpart[2]+scpart[3]);
    float logZ = LN2 * (L2 + PSC*1024.0f + __builtin_amdgcn_logf(Sf) - 2.0f);
    out[b] = sct - logZ;
  }
}

extern "C" void kernel_launch(void* const* d_in, const int* in_sizes, int n_in,
                              void* d_out, int out_size, void* d_ws, size_t ws_size,
                              hipStream_t stream)
{
  patcrf_fwd<<<NB, 256, 0, stream>>>(
    (const float*)d_in[0],          // label_emissions [B,S,32]
    (const float*)d_in[1],          // pattern_emissions [B,S,4]
    (const int*)d_in[2],            // y [B,S]
    (const float*)d_in[3],          // label_transitions [32,32]
    (const int*)d_in[4],            // tag2label [64]
    (const float*)d_in[5],          // tag_patterns [64,4]
    (const float*)d_in[6],          // transition_constraints [64,64]
    (const unsigned int*)d_in[7],   // start_mask [64] (repr sniffed)
    (float*)d_out);
}